// Round 8
// baseline (429.960 us; speedup 1.0000x reference)
//
#include <hip/hip_runtime.h>
#include <cstddef>

// Problem constants (match reference)
#define BATCH 4
#define SEQ   4096
#define DIM   1024
#define KCONV 4
#define EPSV  1e-6f
#define MROWS (BATCH * SEQ)      // 16384
#define CHUNK 8
#define NCHUNK (SEQ / CHUNK)     // 512

using short8v = __attribute__((ext_vector_type(8))) short;  // 8 bf16 (4 VGPRs)
using f32x4   = __attribute__((ext_vector_type(4))) float;  // MFMA acc

// bf16 helpers (RNE)
__device__ __forceinline__ unsigned short f2bf_rne(float f) {
  unsigned int u = __float_as_uint(f);
  u += 0x7FFFu + ((u >> 16) & 1u);
  return (unsigned short)(u >> 16);
}
__device__ __forceinline__ float bf2f(unsigned short h) {
  return __uint_as_float((unsigned int)h << 16);
}

// Full-wave (64-lane) sum reduction; all lanes get the total.
__device__ __forceinline__ float wave_reduce_sum(float v) {
#pragma unroll
  for (int off = 32; off > 0; off >>= 1)
    v += __shfl_xor(v, off, 64);
  return v;
}

// ---------------------------------------------------------------------------
// splitx: fused input RMSNorm + bf16 hi/lo split. One WAVE per row.
// ---------------------------------------------------------------------------
__global__ __launch_bounds__(256) void splitx_kernel(
    const float* __restrict__ x, const float* __restrict__ norm_w,
    unsigned short* __restrict__ Xhi, unsigned short* __restrict__ Xlo) {
  const int row = blockIdx.x * 4 + (threadIdx.x >> 6);
  const int lane = threadIdx.x & 63;
  float4 v[4];
  float ss = 0.f;
#pragma unroll
  for (int i = 0; i < 4; ++i) {
    v[i] = *reinterpret_cast<const float4*>(
        &x[(size_t)row * DIM + lane * 4 + i * 256]);
    ss += v[i].x * v[i].x + v[i].y * v[i].y + v[i].z * v[i].z + v[i].w * v[i].w;
  }
  const float rstd = rsqrtf(wave_reduce_sum(ss) * (1.0f / DIM) + EPSV);
#pragma unroll
  for (int i = 0; i < 4; ++i) {
    const int d4 = lane * 4 + i * 256;
    const float4 w = *reinterpret_cast<const float4*>(&norm_w[d4]);
    const float hv[4] = {v[i].x * rstd * w.x, v[i].y * rstd * w.y,
                         v[i].z * rstd * w.z, v[i].w * rstd * w.w};
    ushort4 hh, ll;
    hh.x = f2bf_rne(hv[0]); ll.x = f2bf_rne(hv[0] - bf2f(hh.x));
    hh.y = f2bf_rne(hv[1]); ll.y = f2bf_rne(hv[1] - bf2f(hh.y));
    hh.z = f2bf_rne(hv[2]); ll.z = f2bf_rne(hv[2] - bf2f(hh.z));
    hh.w = f2bf_rne(hv[3]); ll.w = f2bf_rne(hv[3] - bf2f(hh.w));
    *reinterpret_cast<ushort4*>(&Xhi[(size_t)row * DIM + d4]) = hh;
    *reinterpret_cast<ushort4*>(&Xlo[(size_t)row * DIM + d4]) = ll;
  }
}

// ---------------------------------------------------------------------------
// splitw2: both weights in one launch (blockIdx.z selects).
// W[K][N] fp32 -> transposed bf16 hi/lo Wt[N][K] via 32x32 LDS tiles.
// ---------------------------------------------------------------------------
__global__ __launch_bounds__(256) void splitw2_kernel(
    const float* __restrict__ W0, unsigned short* __restrict__ W0hi,
    unsigned short* __restrict__ W0lo, const float* __restrict__ W1,
    unsigned short* __restrict__ W1hi, unsigned short* __restrict__ W1lo) {
  const float* W; unsigned short *Whi, *Wlo; int N;
  if (blockIdx.z == 0) { W = W0; Whi = W0hi; Wlo = W0lo; N = 2048; }
  else {
    if (blockIdx.x >= 32) return;   // uniform: whole block exits together
    W = W1; Whi = W1hi; Wlo = W1lo; N = 1024;
  }
  const int K = 1024;
  __shared__ float t[32][33];
  const int n0 = blockIdx.x * 32, k0 = blockIdx.y * 32;
  const int c = threadIdx.x & 31, r = threadIdx.x >> 5;  // r: 0..7
#pragma unroll
  for (int i = 0; i < 4; ++i)
    t[r + i * 8][c] = W[(size_t)(k0 + r + i * 8) * N + n0 + c];
  __syncthreads();
#pragma unroll
  for (int i = 0; i < 4; ++i) {
    const int n = n0 + r + i * 8, k = k0 + c;
    const float v = t[c][r + i * 8];
    const unsigned short h = f2bf_rne(v);
    Whi[(size_t)n * K + k] = h;
    Wlo[(size_t)n * K + k] = f2bf_rne(v - bf2f(h));
  }
}

// ---------------------------------------------------------------------------
// Shared GEMM body.  C[M][N] = A[M][1024] * B^T[N][1024].
//   NT=4: bf16x3, BK=32, 4 tiles [128][32] bf16 (8KB each).
//   NT=2: plain bf16, BK=64, 2 tiles [128][64] bf16 (16KB each) — half the
//         barrier/drain count, 32 MFMA per drain.
// LDS 32KB in both. global_load_lds width-16, linear dest; XOR swizzle
// b ^= ((b>>7)&7)<<4 applied to SOURCE logical byte and frag READ byte.
// RULE: any offset relative to a swizzled address must COMPOSE with the
// XOR — sub-step advance of +64B within a row is addr^64 (bit 6 may be
// occupied by the swizzle), tile offsets (+8KB/+16KB, bit 13+) commute.
// Round-6 bug: used aoff+kk*64B (ADD) -> carry into row bit for rows with
// (row&4) -> NaN. Fixed to XOR (ushort idx ^ kk*32).
// ---------------------------------------------------------------------------
template <int NT, bool RESID, bool OBF16>
__device__ __forceinline__ void gemm_body(
    const unsigned short* __restrict__ Ahi, const unsigned short* __restrict__ Alo,
    const unsigned short* __restrict__ Bhi, const unsigned short* __restrict__ Blo,
    float* __restrict__ Cf, unsigned short* __restrict__ Ch, int N, int lda,
    const float* __restrict__ resid, const float* __restrict__ res_scale) {
  constexpr int BK = (NT == 4) ? 32 : 64;
  __shared__ __align__(16) unsigned short lds[16384];  // 32 KB

  const int tid = threadIdx.x;
  const int lane = tid & 63;
  const int wr = tid >> 7;         // wave quadrant row (0..1)
  const int wc = (tid >> 6) & 1;   // wave quadrant col (0..1)

  // XCD-aware block swizzle (nwg divisible by 8 for all GEMMs here)
  const int nwg = gridDim.x * gridDim.y;
  int id = blockIdx.y * gridDim.x + blockIdx.x;
  id = (id & 7) * (nwg >> 3) + (id >> 3);
  const int bx = id % gridDim.x;
  const int by = id / gridDim.x;
  const int bm = by * 128;
  const int bn = bx * 128;

  // Staging: 8 x 16B per thread per K-step (32KB). Linear LDS byte o;
  // tensor t; within-tile ot; source logical byte b = ot^swz(ot).
  const unsigned short* pg[8];
  unsigned int lofs[8];
#pragma unroll
  for (int i = 0; i < 8; ++i) {
    const int o = tid * 16 + i * 4096;
    int t, r, ck;
    if constexpr (NT == 4) {
      t = o >> 13;
      const int ot = o & 8191;
      const int b = ot ^ (((ot >> 7) & 7) << 4);
      r = b >> 6; ck = (b & 63) >> 1;
    } else {
      t = o >> 14;
      const int ot = o & 16383;
      const int b = ot ^ (((ot >> 7) & 7) << 4);
      r = b >> 7; ck = (b & 127) >> 1;
    }
    const unsigned short* base;
    bool aside;
    if constexpr (NT == 4) {
      base = (t == 0) ? Ahi : (t == 1) ? Alo : (t == 2) ? Bhi : Blo;
      aside = (t < 2);
    } else {
      base = (t == 0) ? Ahi : Bhi;
      aside = (t == 0);
    }
    const int stride = aside ? lda : 1024;
    const int rowg = (aside ? bm : bn) + r;
    pg[i] = base + (size_t)rowg * stride + ck;
    lofs[i] = (unsigned int)(o >> 1);
  }

  // Fragment read offsets (ushort idx), swizzled. B tiles at +8192 ushorts
  // in both layouts (NT=4: tile 2 of 4x8KB; NT=2: tile 1 of 2x16KB).
  constexpr int ROWB = (NT == 4) ? 64 : 128;
  unsigned int aoff[4], boff[4];
#pragma unroll
  for (int i = 0; i < 4; ++i) {
    int ba = (wr * 64 + i * 16 + (lane & 15)) * ROWB + (lane >> 4) * 16;
    ba ^= ((ba >> 7) & 7) << 4;
    aoff[i] = (unsigned int)(ba >> 1);
    int bb = (wc * 64 + i * 16 + (lane & 15)) * ROWB + (lane >> 4) * 16;
    bb ^= ((bb >> 7) & 7) << 4;
    boff[i] = (unsigned int)(bb >> 1) + 8192;
  }

  f32x4 acc[4][4];
#pragma unroll
  for (int mi = 0; mi < 4; ++mi)
#pragma unroll
    for (int ni = 0; ni < 4; ++ni) {
      acc[mi][ni][0] = 0.f; acc[mi][ni][1] = 0.f;
      acc[mi][ni][2] = 0.f; acc[mi][ni][3] = 0.f;
    }

  for (int k0 = 0; k0 < 1024; k0 += BK) {
#pragma unroll
    for (int i = 0; i < 8; ++i)
      __builtin_amdgcn_global_load_lds(
          (const __attribute__((address_space(1))) void*)(pg[i] + k0),
          (__attribute__((address_space(3))) void*)(&lds[lofs[i]]), 16, 0, 0);
    __syncthreads();  // compiler drains vmcnt before s_barrier

    if constexpr (NT == 4) {
      short8v bh[4], bl[4];
#pragma unroll
      for (int ni = 0; ni < 4; ++ni) {
        bh[ni] = *reinterpret_cast<const short8v*>(&lds[boff[ni]]);
        bl[ni] = *reinterpret_cast<const short8v*>(&lds[boff[ni] + 4096]);
      }
#pragma unroll
      for (int mi = 0; mi < 4; ++mi) {
        const short8v ah = *reinterpret_cast<const short8v*>(&lds[aoff[mi]]);
        const short8v al = *reinterpret_cast<const short8v*>(&lds[aoff[mi] + 4096]);
#pragma unroll
        for (int ni = 0; ni < 4; ++ni) {
          acc[mi][ni] = __builtin_amdgcn_mfma_f32_16x16x32_bf16(ah, bh[ni], acc[mi][ni], 0, 0, 0);
          acc[mi][ni] = __builtin_amdgcn_mfma_f32_16x16x32_bf16(ah, bl[ni], acc[mi][ni], 0, 0, 0);
          acc[mi][ni] = __builtin_amdgcn_mfma_f32_16x16x32_bf16(al, bh[ni], acc[mi][ni], 0, 0, 0);
        }
      }
    } else {
#pragma unroll
      for (int kk = 0; kk < 2; ++kk) {   // two 32-k sub-steps within BK=64
        short8v bh[4];
#pragma unroll
        for (int ni = 0; ni < 4; ++ni)
          bh[ni] = *reinterpret_cast<const short8v*>(&lds[boff[ni] ^ (kk * 32)]);
#pragma unroll
        for (int mi = 0; mi < 4; ++mi) {
          const short8v ah =
              *reinterpret_cast<const short8v*>(&lds[aoff[mi] ^ (kk * 32)]);
#pragma unroll
          for (int ni = 0; ni < 4; ++ni)
            acc[mi][ni] = __builtin_amdgcn_mfma_f32_16x16x32_bf16(ah, bh[ni], acc[mi][ni], 0, 0, 0);
        }
      }
    }
    __syncthreads();
  }

  // Epilogue: C/D layout col=lane&15, row=(lane>>4)*4+reg (verified).
  const float rscale = RESID ? res_scale[0] : 0.0f;
#pragma unroll
  for (int mi = 0; mi < 4; ++mi) {
    const int row0 = bm + wr * 64 + mi * 16 + (lane >> 4) * 4;
#pragma unroll
    for (int ni = 0; ni < 4; ++ni) {
      const int col = bn + wc * 64 + ni * 16 + (lane & 15);
#pragma unroll
      for (int r = 0; r < 4; ++r) {
        const size_t idx = (size_t)(row0 + r) * N + col;
        float v = acc[mi][ni][r];
        if constexpr (RESID) v = fmaf(resid[idx], rscale, v);
        if constexpr (OBF16) Ch[idx] = f2bf_rne(v);
        else                 Cf[idx] = v;
      }
    }
  }
}

// Distinctly named wrappers so rocprof rows are attributable per GEMM.
__global__ __launch_bounds__(256) void gemm1a_kernel(
    const unsigned short* Ahi, const unsigned short* Alo,
    const unsigned short* Bhi, const unsigned short* Blo, float* Cf) {
  gemm_body<4, false, false>(Ahi, Alo, Bhi, Blo, Cf, nullptr, DIM, 1024,
                             nullptr, nullptr);
}
__global__ __launch_bounds__(256) void gemm1z_kernel(
    const unsigned short* Ahi, const unsigned short* Bhi, unsigned short* Ch) {
  gemm_body<2, false, true>(Ahi, nullptr, Bhi, nullptr, nullptr, Ch, DIM,
                            1024, nullptr, nullptr);
}
__global__ __launch_bounds__(256) void gemm2_kernel(
    const unsigned short* Ahi, const unsigned short* Bhi, float* Cf,
    const float* resid, const float* res_scale) {
  gemm_body<2, true, false>(Ahi, nullptr, Bhi, nullptr, Cf, nullptr, DIM,
                            1024, resid, res_scale);
}

// ---------------------------------------------------------------------------
// Phase A: depthwise causal conv(K=4) + bias + silu + LOCAL scan, CHUNK=8.
// Grid (NCHUNK, BATCH); 256 threads x float4 -> 1024 d's. 16B/lane loads.
// ---------------------------------------------------------------------------
__global__ __launch_bounds__(256) void phaseA_kernel(
    const float* __restrict__ xb, const float* __restrict__ conv_w,
    const float* __restrict__ conv_b, const float* __restrict__ decay,
    float* __restrict__ hs, float* __restrict__ fbuf) {
  const int d = threadIdx.x * 4;
  const int c = blockIdx.x;
  const int b = blockIdx.y;
  const int t0 = c * CHUNK;

  float cw[4][4];
#pragma unroll
  for (int j = 0; j < 4; ++j) {
    const float4 w = *reinterpret_cast<const float4*>(&conv_w[(d + j) * 4]);
    cw[j][0] = w.x; cw[j][1] = w.y; cw[j][2] = w.z; cw[j][3] = w.w;
  }
  const float4 cb4 = *reinterpret_cast<const float4*>(&conv_b[d]);
  const float4 dc4 = *reinterpret_cast<const float4*>(&decay[d]);
  const float cb[4] = {cb4.x, cb4.y, cb4.z, cb4.w};
  const float a[4] = {
      1.0f / (1.0f + expf(-dc4.x)), 1.0f / (1.0f + expf(-dc4.y)),
      1.0f / (1.0f + expf(-dc4.z)), 1.0f / (1.0f + expf(-dc4.w))};

  const size_t base = ((size_t)b * SEQ + t0) * DIM + d;
  float p1[4] = {0, 0, 0, 0}, p2[4] = {0, 0, 0, 0}, p3[4] = {0, 0, 0, 0};
  if (t0 >= 1) {
    const float4 v = *reinterpret_cast<const float4*>(&xb[base - DIM]);
    p1[0] = v.x; p1[1] = v.y; p1[2] = v.z; p1[3] = v.w;
  }
  if (t0 >= 2) {
    const float4 v = *reinterpret_cast<const float4*>(&xb[base - 2 * DIM]);
    p2[0] = v.x; p2[1] = v.y; p2[2] = v.z; p2[3] = v.w;
  }
  if (t0 >= 3) {
    const float4 v = *reinterpret_cast<const float4*>(&xb[base - 3 * DIM]);
    p3[0] = v.x; p3[1] = v.y; p3[2] = v.z; p3[3] = v.w;
  }

  float h[4] = {0, 0, 0, 0};
  size_t src = base;
#pragma unroll
  for (int t = 0; t < CHUNK; ++t) {
    const float4 cv = *reinterpret_cast<const float4*>(&xb[src]);
    const float cur[4] = {cv.x, cv.y, cv.z, cv.w};
    float4 ho;
    float* hp = &ho.x;
#pragma unroll
    for (int j = 0; j < 4; ++j) {
      const float conv = fmaf(cw[j][0], p3[j],
                         fmaf(cw[j][1], p2[j],
                         fmaf(cw[j][2], p1[j],
                         fmaf(cw[j][3], cur[j], cb[j]))));
      const float u = conv / (1.0f + expf(-conv));  // silu
      h[j] = fmaf(a[j], h[j], u);
      hp[j] = h[j];
      p3[j] = p2[j]; p2[j] = p1[j]; p1[j] = cur[j];
    }
    *reinterpret_cast<float4*>(&hs[src]) = ho;
    src += DIM;
  }
  float4 fo; fo.x = h[0]; fo.y = h[1]; fo.z = h[2]; fo.w = h[3];
  *reinterpret_cast<float4*>(&fbuf[((size_t)b * NCHUNK + c) * DIM + d]) = fo;
}

// ---------------------------------------------------------------------------
// Phase B: sequential carry propagation across 512 chunks, 16-deep prefetch.
// Grid: (DIM/256, BATCH).
// ---------------------------------------------------------------------------
__global__ __launch_bounds__(256) void phaseB_kernel(
    const float* __restrict__ decay, const float* __restrict__ fbuf,
    float* __restrict__ cbuf) {
  const int d = blockIdx.x * 256 + threadIdx.x;
  const int b = blockIdx.y;
  const float a = 1.0f / (1.0f + expf(-decay[d]));
  const float aL = exp2f((float)CHUNK * __log2f(a));
  const float* fp = fbuf + (size_t)b * NCHUNK * DIM + d;
  float* cp = cbuf + (size_t)b * NCHUNK * DIM + d;
  float carry = 0.f;
  for (int c0 = 0; c0 < NCHUNK; c0 += 16) {
    float v[16];
#pragma unroll
    for (int i = 0; i < 16; ++i) v[i] = fp[(size_t)(c0 + i) * DIM];
#pragma unroll
    for (int i = 0; i < 16; ++i) {
      cp[(size_t)(c0 + i) * DIM] = carry;
      carry = fmaf(aL, carry, v[i]);
    }
  }
}

// ---------------------------------------------------------------------------
// Phase C: h_full = hs_local + a^(j+1)*carry; y = rmsnorm(h_full, gate_w) *
// silu(z) -> bf16. One WAVE per row; 4 rows per block. CHUNK=8.
// ---------------------------------------------------------------------------
__global__ __launch_bounds__(256) void phaseC_kernel(
    const unsigned short* __restrict__ z, const float* __restrict__ hs,
    const float* __restrict__ cbuf, const float* __restrict__ decay,
    const float* __restrict__ gate_w, unsigned short* __restrict__ Yhi) {
  const int row = blockIdx.x * 4 + (threadIdx.x >> 6);
  const int lane = threadIdx.x & 63;
  const int b = row >> 12;             // SEQ = 4096
  const int t = row & (SEQ - 1);
  const int c = t >> 3;                // CHUNK = 8
  const float e = (float)((t & (CHUNK - 1)) + 1);

  float hv[16];
  float ss = 0.f;
#pragma unroll
  for (int i = 0; i < 4; ++i) {
    const int d4 = lane * 4 + i * 256;
    const float4 dc = *reinterpret_cast<const float4*>(&decay[d4]);
    const float4 cv = *reinterpret_cast<const float4*>(
        &cbuf[((size_t)b * NCHUNK + c) * DIM + d4]);
    const float4 hl = *reinterpret_cast<const float4*>(
        &hs[(size_t)row * DIM + d4]);
    const float ad[4] = {dc.x, dc.y, dc.z, dc.w};
    const float cr[4] = {cv.x, cv.y, cv.z, cv.w};
    const float hh[4] = {hl.x, hl.y, hl.z, hl.w};
#pragma unroll
    for (int j = 0; j < 4; ++j) {
      const float a = 1.0f / (1.0f + expf(-ad[j]));
      const float ae = exp2f(e * __log2f(a));
      const float v = fmaf(ae, cr[j], hh[j]);
      hv[i * 4 + j] = v;
      ss = fmaf(v, v, ss);
    }
  }
  const float rstd = rsqrtf(wave_reduce_sum(ss) * (1.0f / DIM) + EPSV);
#pragma unroll
  for (int i = 0; i < 4; ++i) {
    const int d4 = lane * 4 + i * 256;
    const ushort4 zs = *reinterpret_cast<const ushort4*>(
        &z[(size_t)row * DIM + d4]);
    const float4 gw = *reinterpret_cast<const float4*>(&gate_w[d4]);
    const float zf[4] = {bf2f(zs.x), bf2f(zs.y), bf2f(zs.z), bf2f(zs.w)};
    const float gf[4] = {gw.x, gw.y, gw.z, gw.w};
    ushort4 yo;
    unsigned short* yp = &yo.x;
#pragma unroll
    for (int j = 0; j < 4; ++j) {
      const float sz = zf[j] / (1.0f + expf(-zf[j]));  // silu(z)
      yp[j] = f2bf_rne(hv[i * 4 + j] * rstd * gf[j] * sz);
    }
    *reinterpret_cast<ushort4*>(&Yhi[(size_t)row * DIM + d4]) = yo;
  }
}

// ---------------------------------------------------------------------------
extern "C" void kernel_launch(void* const* d_in, const int* in_sizes, int n_in,
                              void* d_out, int out_size, void* d_ws,
                              size_t ws_size, hipStream_t stream) {
  const float* x = (const float*)d_in[0];
  const float* norm_w = (const float*)d_in[1];
  const float* in_w = (const float*)d_in[2];
  const float* conv_w = (const float*)d_in[3];
  const float* conv_b = (const float*)d_in[4];
  const float* decay = (const float*)d_in[5];
  const float* gate_w = (const float*)d_in[6];
  const float* out_w = (const float*)d_in[7];
  const float* res_scale = (const float*)d_in[8];
  float* out = (float*)d_out;

  // Workspace layout (bytes), peak 213,909,504 (~204 MiB):
  //  [0,       67.1M)  xb fp32 [M][1024]   (GEMM1a out; phaseA in)
  //  [67.1M,  100.7M)  z  bf16 [M][1024]   (GEMM1z out; phaseC in)
  //  [100.7M, 134.2M)  yhi bf16 [M][1024]  (phaseC out; GEMM2 A)
  //  [134.2M, 201.3M)  xhi|xlo bf16        (GEMM1 A); dead after GEMM1z ->
  //                    hs fp32 [M][1024] overlays it (phaseA out, phaseC in)
  //  [201.3M, 213.9M)  w1hi|w1lo|w2hi|w2lo (bf16, transposed)
  //  fbuf/cbuf (8 MB each) live in d_out scratch (dead until GEMM2).
  const size_t NEEDED = 213909504;
  if (ws_size < NEEDED) return;  // clean diagnostic fail instead of OOB fault

  char* w8 = (char*)d_ws;
  float* xb = (float*)(w8);
  unsigned short* zbf = (unsigned short*)(w8 + 67108864);
  unsigned short* yhi = (unsigned short*)(w8 + 100663296);
  unsigned short* xhi = (unsigned short*)(w8 + 134217728);
  unsigned short* xlo = (unsigned short*)(w8 + 167772160);
  float* hs = (float*)(w8 + 134217728);            // overlays xhi/xlo
  unsigned short* w1hi = (unsigned short*)(w8 + 201326592);
  unsigned short* w1lo = (unsigned short*)(w8 + 205520896);
  unsigned short* w2hi = (unsigned short*)(w8 + 209715200);
  unsigned short* w2lo = (unsigned short*)(w8 + 211812352);
  float* fbuf = (float*)d_out;                     // scratch until GEMM2
  float* cbuf = fbuf + (size_t)BATCH * NCHUNK * DIM;

  // 1. fused RMSNorm + bf16 split of x (wave per row)
  splitx_kernel<<<MROWS / 4, 256, 0, stream>>>(x, norm_w, xhi, xlo);

  // 2. both weight transpose+splits in one launch
  splitw2_kernel<<<dim3(64, 32, 2), 256, 0, stream>>>(
      in_w, w1hi, w1lo, out_w, w2hi, w2lo);

  // 3. GEMM1a (bf16x3, BK=32): xb = norm(x) @ in_w[:, :1024]   fp32 out
  gemm1a_kernel<<<dim3(8, 128), 256, 0, stream>>>(xhi, xlo, w1hi, w1lo, xb);

  // 4. GEMM1z (bf16x1, BK=64): z = norm(x) @ in_w[:, 1024:]    bf16 out
  gemm1z_kernel<<<dim3(8, 128), 256, 0, stream>>>(
      xhi, w1hi + (size_t)1024 * 1024, zbf);

  // 5. conv + silu + local scan (CHUNK=8, float4/thread)
  phaseA_kernel<<<dim3(NCHUNK, BATCH), 256, 0, stream>>>(
      xb, conv_w, conv_b, decay, hs, fbuf);

  // 6. chunk carry propagation (16-deep prefetch)
  phaseB_kernel<<<dim3(DIM / 256, BATCH), 256, 0, stream>>>(decay, fbuf, cbuf);

  // 7. carry injection + gated rmsnorm * silu(z) -> yhi (bf16)
  phaseC_kernel<<<MROWS / 4, 256, 0, stream>>>(zbf, hs, cbuf, decay, gate_w, yhi);

  // 8. GEMM2 (bf16x1, BK=64): out = x * res_scale + y @ out_w
  gemm2_kernel<<<dim3(8, 128), 256, 0, stream>>>(yhi, w2hi, out, x, res_scale);
}

// Round 10
// 404.809 us; speedup vs baseline: 1.0621x; 1.0621x over previous
//
#include <hip/hip_runtime.h>
#include <cstddef>

// Problem constants (match reference)
#define BATCH 4
#define SEQ   4096
#define DIM   1024
#define KCONV 4
#define EPSV  1e-6f
#define MROWS (BATCH * SEQ)      // 16384
#define CHUNK 8
#define NCHUNK (SEQ / CHUNK)     // 512

using short8v = __attribute__((ext_vector_type(8))) short;  // 8 bf16 (4 VGPRs)
using f32x4   = __attribute__((ext_vector_type(4))) float;  // MFMA acc

// bf16 helpers (RNE)
__device__ __forceinline__ unsigned short f2bf_rne(float f) {
  unsigned int u = __float_as_uint(f);
  u += 0x7FFFu + ((u >> 16) & 1u);
  return (unsigned short)(u >> 16);
}
__device__ __forceinline__ float bf2f(unsigned short h) {
  return __uint_as_float((unsigned int)h << 16);
}

// Full-wave (64-lane) sum reduction; all lanes get the total.
__device__ __forceinline__ float wave_reduce_sum(float v) {
#pragma unroll
  for (int off = 32; off > 0; off >>= 1)
    v += __shfl_xor(v, off, 64);
  return v;
}

// ---------------------------------------------------------------------------
// splitx: fused input RMSNorm + bf16 round (hi only; exact-B GEMM1 needs no
// A-lo stream). One WAVE per row; 4 rows per block.
// ---------------------------------------------------------------------------
__global__ __launch_bounds__(256) void splitx_kernel(
    const float* __restrict__ x, const float* __restrict__ norm_w,
    unsigned short* __restrict__ Xhi) {
  const int row = blockIdx.x * 4 + (threadIdx.x >> 6);
  const int lane = threadIdx.x & 63;
  float4 v[4];
  float ss = 0.f;
#pragma unroll
  for (int i = 0; i < 4; ++i) {
    v[i] = *reinterpret_cast<const float4*>(
        &x[(size_t)row * DIM + lane * 4 + i * 256]);
    ss += v[i].x * v[i].x + v[i].y * v[i].y + v[i].z * v[i].z + v[i].w * v[i].w;
  }
  const float rstd = rsqrtf(wave_reduce_sum(ss) * (1.0f / DIM) + EPSV);
#pragma unroll
  for (int i = 0; i < 4; ++i) {
    const int d4 = lane * 4 + i * 256;
    const float4 w = *reinterpret_cast<const float4*>(&norm_w[d4]);
    ushort4 hh;
    hh.x = f2bf_rne(v[i].x * rstd * w.x);
    hh.y = f2bf_rne(v[i].y * rstd * w.y);
    hh.z = f2bf_rne(v[i].z * rstd * w.z);
    hh.w = f2bf_rne(v[i].w * rstd * w.w);
    *reinterpret_cast<ushort4*>(&Xhi[(size_t)row * DIM + d4]) = hh;
  }
}

// ---------------------------------------------------------------------------
// splitw2: both weights in one launch (blockIdx.z selects).
// W[K][N] fp32 -> transposed bf16 hi/lo Wt[N][K] via 32x32 LDS tiles.
// ---------------------------------------------------------------------------
__global__ __launch_bounds__(256) void splitw2_kernel(
    const float* __restrict__ W0, unsigned short* __restrict__ W0hi,
    unsigned short* __restrict__ W0lo, const float* __restrict__ W1,
    unsigned short* __restrict__ W1hi, unsigned short* __restrict__ W1lo) {
  const float* W; unsigned short *Whi, *Wlo; int N;
  if (blockIdx.z == 0) { W = W0; Whi = W0hi; Wlo = W0lo; N = 2048; }
  else {
    if (blockIdx.x >= 32) return;   // uniform: whole block exits together
    W = W1; Whi = W1hi; Wlo = W1lo; N = 1024;
  }
  const int K = 1024;
  __shared__ float t[32][33];
  const int n0 = blockIdx.x * 32, k0 = blockIdx.y * 32;
  const int c = threadIdx.x & 31, r = threadIdx.x >> 5;  // r: 0..7
#pragma unroll
  for (int i = 0; i < 4; ++i)
    t[r + i * 8][c] = W[(size_t)(k0 + r + i * 8) * N + n0 + c];
  __syncthreads();
#pragma unroll
  for (int i = 0; i < 4; ++i) {
    const int n = n0 + r + i * 8, k = k0 + c;
    const float v = t[c][r + i * 8];
    const unsigned short h = f2bf_rne(v);
    Whi[(size_t)n * K + k] = h;
    Wlo[(size_t)n * K + k] = f2bf_rne(v - bf2f(h));
  }
}

// ---------------------------------------------------------------------------
// Shared GEMM body.  C[M][N] = A[M][1024] * B^T[N][1024].
//   NT=4: exact-B bf16x2 on the PROVEN 4-tile structure: stages Ahi,Alo,
//         Bhi,Blo exactly as the verified bf16x3 kernel (BK=32, 32KB LDS),
//         but computes only C = Ahi*(Bhi+Blo) — 2 MFMA/frag-pair, 32/step.
//         The Alo LDS tile is staged but never read (values irrelevant).
//         [Round-9 lesson: 3-tile restructure NaN'd undiagnosed; this keeps
//          staging byte-identical to the round-8 pass and changes ONLY the
//          MFMA loop.]
//   NT=2: plain bf16, BK=64, 2 tiles [128][64] (32KB), XOR sub-step advance.
// global_load_lds width-16, linear dest; XOR swizzle b ^= ((b>>7)&7)<<4 on
// SOURCE logical byte and frag READ byte (involution, both sides).
// RULE: offsets vs swizzled addrs must COMPOSE with the XOR — +64B within a
// row is addr^64; tile offsets (bit 13+) commute (round-6 lesson).
// ---------------------------------------------------------------------------
template <int NT, bool RESID, bool OBF16>
__device__ __forceinline__ void gemm_body(
    const unsigned short* __restrict__ Ahi, const unsigned short* __restrict__ Alo,
    const unsigned short* __restrict__ Bhi, const unsigned short* __restrict__ Blo,
    float* __restrict__ Cf, unsigned short* __restrict__ Ch, int N, int lda,
    const float* __restrict__ resid, const float* __restrict__ res_scale) {
  constexpr int BK = (NT == 4) ? 32 : 64;
  __shared__ __align__(16) unsigned short lds[16384];  // 32 KB

  const int tid = threadIdx.x;
  const int lane = tid & 63;
  const int wr = tid >> 7;         // wave quadrant row (0..1)
  const int wc = (tid >> 6) & 1;   // wave quadrant col (0..1)

  // XCD-aware block swizzle (nwg divisible by 8 for all GEMMs here)
  const int nwg = gridDim.x * gridDim.y;
  int id = blockIdx.y * gridDim.x + blockIdx.x;
  id = (id & 7) * (nwg >> 3) + (id >> 3);
  const int bx = id % gridDim.x;
  const int by = id / gridDim.x;
  const int bm = by * 128;
  const int bn = bx * 128;

  // Staging: 8 x 16B per thread per K-step (32KB). Linear LDS byte o;
  // tensor t; within-tile ot; source logical byte b = ot^swz(ot).
  const unsigned short* pg[8];
  unsigned int lofs[8];
#pragma unroll
  for (int i = 0; i < 8; ++i) {
    const int o = tid * 16 + i * 4096;
    int t, r, ck;
    if constexpr (NT == 4) {
      t = o >> 13;
      const int ot = o & 8191;
      const int b = ot ^ (((ot >> 7) & 7) << 4);
      r = b >> 6; ck = (b & 63) >> 1;
    } else {
      t = o >> 14;
      const int ot = o & 16383;
      const int b = ot ^ (((ot >> 7) & 7) << 4);
      r = b >> 7; ck = (b & 127) >> 1;
    }
    const unsigned short* base;
    bool aside;
    if constexpr (NT == 4) {
      base = (t == 0) ? Ahi : (t == 1) ? Alo : (t == 2) ? Bhi : Blo;
      aside = (t < 2);
    } else {
      base = (t == 0) ? Ahi : Bhi;
      aside = (t == 0);
    }
    const int stride = aside ? lda : 1024;
    const int rowg = (aside ? bm : bn) + r;
    pg[i] = base + (size_t)rowg * stride + ck;
    lofs[i] = (unsigned int)(o >> 1);
  }

  // Fragment read offsets (ushort idx), swizzled. B tiles at +8192 ushorts
  // in both layouts (NT=4: tile 2 of 4x8KB; NT=2: tile 1 of 2x16KB).
  constexpr int ROWB = (NT == 4) ? 64 : 128;
  unsigned int aoff[4], boff[4];
#pragma unroll
  for (int i = 0; i < 4; ++i) {
    int ba = (wr * 64 + i * 16 + (lane & 15)) * ROWB + (lane >> 4) * 16;
    ba ^= ((ba >> 7) & 7) << 4;
    aoff[i] = (unsigned int)(ba >> 1);
    int bb = (wc * 64 + i * 16 + (lane & 15)) * ROWB + (lane >> 4) * 16;
    bb ^= ((bb >> 7) & 7) << 4;
    boff[i] = (unsigned int)(bb >> 1) + 8192;
  }

  f32x4 acc[4][4];
#pragma unroll
  for (int mi = 0; mi < 4; ++mi)
#pragma unroll
    for (int ni = 0; ni < 4; ++ni) {
      acc[mi][ni][0] = 0.f; acc[mi][ni][1] = 0.f;
      acc[mi][ni][2] = 0.f; acc[mi][ni][3] = 0.f;
    }

  for (int k0 = 0; k0 < 1024; k0 += BK) {
#pragma unroll
    for (int i = 0; i < 8; ++i)
      __builtin_amdgcn_global_load_lds(
          (const __attribute__((address_space(1))) void*)(pg[i] + k0),
          (__attribute__((address_space(3))) void*)(&lds[lofs[i]]), 16, 0, 0);
    __syncthreads();  // compiler drains vmcnt before s_barrier

    if constexpr (NT == 4) {
      // exact-B: C += Ahi*(Bhi + Blo). Alo tile never read.
      short8v bh[4], bl[4];
#pragma unroll
      for (int ni = 0; ni < 4; ++ni) {
        bh[ni] = *reinterpret_cast<const short8v*>(&lds[boff[ni]]);
        bl[ni] = *reinterpret_cast<const short8v*>(&lds[boff[ni] + 4096]);
      }
#pragma unroll
      for (int mi = 0; mi < 4; ++mi) {
        const short8v ah = *reinterpret_cast<const short8v*>(&lds[aoff[mi]]);
#pragma unroll
        for (int ni = 0; ni < 4; ++ni) {
          acc[mi][ni] = __builtin_amdgcn_mfma_f32_16x16x32_bf16(ah, bh[ni], acc[mi][ni], 0, 0, 0);
          acc[mi][ni] = __builtin_amdgcn_mfma_f32_16x16x32_bf16(ah, bl[ni], acc[mi][ni], 0, 0, 0);
        }
      }
    } else {
#pragma unroll
      for (int kk = 0; kk < 2; ++kk) {   // two 32-k sub-steps within BK=64
        short8v bh[4];
#pragma unroll
        for (int ni = 0; ni < 4; ++ni)
          bh[ni] = *reinterpret_cast<const short8v*>(&lds[boff[ni] ^ (kk * 32)]);
#pragma unroll
        for (int mi = 0; mi < 4; ++mi) {
          const short8v ah =
              *reinterpret_cast<const short8v*>(&lds[aoff[mi] ^ (kk * 32)]);
#pragma unroll
          for (int ni = 0; ni < 4; ++ni)
            acc[mi][ni] = __builtin_amdgcn_mfma_f32_16x16x32_bf16(ah, bh[ni], acc[mi][ni], 0, 0, 0);
        }
      }
    }
    __syncthreads();
  }

  // Epilogue: C/D layout col=lane&15, row=(lane>>4)*4+reg (verified).
  const float rscale = RESID ? res_scale[0] : 0.0f;
#pragma unroll
  for (int mi = 0; mi < 4; ++mi) {
    const int row0 = bm + wr * 64 + mi * 16 + (lane >> 4) * 4;
#pragma unroll
    for (int ni = 0; ni < 4; ++ni) {
      const int col = bn + wc * 64 + ni * 16 + (lane & 15);
#pragma unroll
      for (int r = 0; r < 4; ++r) {
        const size_t idx = (size_t)(row0 + r) * N + col;
        float v = acc[mi][ni][r];
        if constexpr (RESID) v = fmaf(resid[idx], rscale, v);
        if constexpr (OBF16) Ch[idx] = f2bf_rne(v);
        else                 Cf[idx] = v;
      }
    }
  }
}

// Distinctly named wrappers so rocprof rows are attributable per GEMM.
__global__ __launch_bounds__(256) void gemm1a_kernel(
    const unsigned short* Ahi, const unsigned short* Alo,
    const unsigned short* Bhi, const unsigned short* Blo, float* Cf) {
  gemm_body<4, false, false>(Ahi, Alo, Bhi, Blo, Cf, nullptr, DIM, 1024,
                             nullptr, nullptr);
}
__global__ __launch_bounds__(256) void gemm1z_kernel(
    const unsigned short* Ahi, const unsigned short* Bhi, unsigned short* Ch) {
  gemm_body<2, false, true>(Ahi, nullptr, Bhi, nullptr, nullptr, Ch, DIM,
                            1024, nullptr, nullptr);
}
__global__ __launch_bounds__(256) void gemm2_kernel(
    const unsigned short* Ahi, const unsigned short* Bhi, float* Cf,
    const float* resid, const float* res_scale) {
  gemm_body<2, true, false>(Ahi, nullptr, Bhi, nullptr, Cf, nullptr, DIM,
                            1024, resid, res_scale);
}

// ---------------------------------------------------------------------------
// Phase A: depthwise causal conv(K=4) + bias + silu + LOCAL scan, CHUNK=8.
// Grid (NCHUNK, BATCH); 256 threads x float4 -> 1024 d's. 16B/lane loads.
// ---------------------------------------------------------------------------
__global__ __launch_bounds__(256) void phaseA_kernel(
    const float* __restrict__ xb, const float* __restrict__ conv_w,
    const float* __restrict__ conv_b, const float* __restrict__ decay,
    float* __restrict__ hs, float* __restrict__ fbuf) {
  const int d = threadIdx.x * 4;
  const int c = blockIdx.x;
  const int b = blockIdx.y;
  const int t0 = c * CHUNK;

  float cw[4][4];
#pragma unroll
  for (int j = 0; j < 4; ++j) {
    const float4 w = *reinterpret_cast<const float4*>(&conv_w[(d + j) * 4]);
    cw[j][0] = w.x; cw[j][1] = w.y; cw[j][2] = w.z; cw[j][3] = w.w;
  }
  const float4 cb4 = *reinterpret_cast<const float4*>(&conv_b[d]);
  const float4 dc4 = *reinterpret_cast<const float4*>(&decay[d]);
  const float cb[4] = {cb4.x, cb4.y, cb4.z, cb4.w};
  const float a[4] = {
      1.0f / (1.0f + expf(-dc4.x)), 1.0f / (1.0f + expf(-dc4.y)),
      1.0f / (1.0f + expf(-dc4.z)), 1.0f / (1.0f + expf(-dc4.w))};

  const size_t base = ((size_t)b * SEQ + t0) * DIM + d;
  float p1[4] = {0, 0, 0, 0}, p2[4] = {0, 0, 0, 0}, p3[4] = {0, 0, 0, 0};
  if (t0 >= 1) {
    const float4 v = *reinterpret_cast<const float4*>(&xb[base - DIM]);
    p1[0] = v.x; p1[1] = v.y; p1[2] = v.z; p1[3] = v.w;
  }
  if (t0 >= 2) {
    const float4 v = *reinterpret_cast<const float4*>(&xb[base - 2 * DIM]);
    p2[0] = v.x; p2[1] = v.y; p2[2] = v.z; p2[3] = v.w;
  }
  if (t0 >= 3) {
    const float4 v = *reinterpret_cast<const float4*>(&xb[base - 3 * DIM]);
    p3[0] = v.x; p3[1] = v.y; p3[2] = v.z; p3[3] = v.w;
  }

  float h[4] = {0, 0, 0, 0};
  size_t src = base;
#pragma unroll
  for (int t = 0; t < CHUNK; ++t) {
    const float4 cv = *reinterpret_cast<const float4*>(&xb[src]);
    const float cur[4] = {cv.x, cv.y, cv.z, cv.w};
    float4 ho;
    float* hp = &ho.x;
#pragma unroll
    for (int j = 0; j < 4; ++j) {
      const float conv = fmaf(cw[j][0], p3[j],
                         fmaf(cw[j][1], p2[j],
                         fmaf(cw[j][2], p1[j],
                         fmaf(cw[j][3], cur[j], cb[j]))));
      const float u = conv / (1.0f + expf(-conv));  // silu
      h[j] = fmaf(a[j], h[j], u);
      hp[j] = h[j];
      p3[j] = p2[j]; p2[j] = p1[j]; p1[j] = cur[j];
    }
    *reinterpret_cast<float4*>(&hs[src]) = ho;
    src += DIM;
  }
  float4 fo; fo.x = h[0]; fo.y = h[1]; fo.z = h[2]; fo.w = h[3];
  *reinterpret_cast<float4*>(&fbuf[((size_t)b * NCHUNK + c) * DIM + d]) = fo;
}

// ---------------------------------------------------------------------------
// Phase B: sequential carry propagation across 512 chunks, 16-deep prefetch.
// Grid: (DIM/256, BATCH).
// ---------------------------------------------------------------------------
__global__ __launch_bounds__(256) void phaseB_kernel(
    const float* __restrict__ decay, const float* __restrict__ fbuf,
    float* __restrict__ cbuf) {
  const int d = blockIdx.x * 256 + threadIdx.x;
  const int b = blockIdx.y;
  const float a = 1.0f / (1.0f + expf(-decay[d]));
  const float aL = exp2f((float)CHUNK * __log2f(a));
  const float* fp = fbuf + (size_t)b * NCHUNK * DIM + d;
  float* cp = cbuf + (size_t)b * NCHUNK * DIM + d;
  float carry = 0.f;
  for (int c0 = 0; c0 < NCHUNK; c0 += 16) {
    float v[16];
#pragma unroll
    for (int i = 0; i < 16; ++i) v[i] = fp[(size_t)(c0 + i) * DIM];
#pragma unroll
    for (int i = 0; i < 16; ++i) {
      cp[(size_t)(c0 + i) * DIM] = carry;
      carry = fmaf(aL, carry, v[i]);
    }
  }
}

// ---------------------------------------------------------------------------
// Phase C: h_full = hs_local + a^(j+1)*carry; y = rmsnorm(h_full, gate_w) *
// silu(z) -> bf16. One WAVE per row; 4 rows per block. CHUNK=8.
// ---------------------------------------------------------------------------
__global__ __launch_bounds__(256) void phaseC_kernel(
    const unsigned short* __restrict__ z, const float* __restrict__ hs,
    const float* __restrict__ cbuf, const float* __restrict__ decay,
    const float* __restrict__ gate_w, unsigned short* __restrict__ Yhi) {
  const int row = blockIdx.x * 4 + (threadIdx.x >> 6);
  const int lane = threadIdx.x & 63;
  const int b = row >> 12;             // SEQ = 4096
  const int t = row & (SEQ - 1);
  const int c = t >> 3;                // CHUNK = 8
  const float e = (float)((t & (CHUNK - 1)) + 1);

  float hv[16];
  float ss = 0.f;
#pragma unroll
  for (int i = 0; i < 4; ++i) {
    const int d4 = lane * 4 + i * 256;
    const float4 dc = *reinterpret_cast<const float4*>(&decay[d4]);
    const float4 cv = *reinterpret_cast<const float4*>(
        &cbuf[((size_t)b * NCHUNK + c) * DIM + d4]);
    const float4 hl = *reinterpret_cast<const float4*>(
        &hs[(size_t)row * DIM + d4]);
    const float ad[4] = {dc.x, dc.y, dc.z, dc.w};
    const float cr[4] = {cv.x, cv.y, cv.z, cv.w};
    const float hh[4] = {hl.x, hl.y, hl.z, hl.w};
#pragma unroll
    for (int j = 0; j < 4; ++j) {
      const float a = 1.0f / (1.0f + expf(-ad[j]));
      const float ae = exp2f(e * __log2f(a));
      const float v = fmaf(ae, cr[j], hh[j]);
      hv[i * 4 + j] = v;
      ss = fmaf(v, v, ss);
    }
  }
  const float rstd = rsqrtf(wave_reduce_sum(ss) * (1.0f / DIM) + EPSV);
#pragma unroll
  for (int i = 0; i < 4; ++i) {
    const int d4 = lane * 4 + i * 256;
    const ushort4 zs = *reinterpret_cast<const ushort4*>(
        &z[(size_t)row * DIM + d4]);
    const float4 gw = *reinterpret_cast<const float4*>(&gate_w[d4]);
    const float zf[4] = {bf2f(zs.x), bf2f(zs.y), bf2f(zs.z), bf2f(zs.w)};
    const float gf[4] = {gw.x, gw.y, gw.z, gw.w};
    ushort4 yo;
    unsigned short* yp = &yo.x;
#pragma unroll
    for (int j = 0; j < 4; ++j) {
      const float sz = zf[j] / (1.0f + expf(-zf[j]));  // silu(z)
      yp[j] = f2bf_rne(hv[i * 4 + j] * rstd * gf[j] * sz);
    }
    *reinterpret_cast<ushort4*>(&Yhi[(size_t)row * DIM + d4]) = yo;
  }
}

// ---------------------------------------------------------------------------
extern "C" void kernel_launch(void* const* d_in, const int* in_sizes, int n_in,
                              void* d_out, int out_size, void* d_ws,
                              size_t ws_size, hipStream_t stream) {
  const float* x = (const float*)d_in[0];
  const float* norm_w = (const float*)d_in[1];
  const float* in_w = (const float*)d_in[2];
  const float* conv_w = (const float*)d_in[3];
  const float* conv_b = (const float*)d_in[4];
  const float* decay = (const float*)d_in[5];
  const float* gate_w = (const float*)d_in[6];
  const float* out_w = (const float*)d_in[7];
  const float* res_scale = (const float*)d_in[8];
  float* out = (float*)d_out;

  // Workspace layout (bytes), peak 213,909,504 (~204 MiB):
  //  [0,       67.1M)  xb fp32 [M][1024]   (GEMM1a out; phaseA in)
  //  [67.1M,  100.7M)  z  bf16 [M][1024]   (GEMM1z out; phaseC in)
  //  [100.7M, 134.2M)  yhi bf16 [M][1024]  (phaseC out; GEMM2 A)
  //  [134.2M, 201.3M)  xhi bf16 (GEMM1 A) — dead after GEMM1z ->
  //                    hs fp32 [M][1024] overlays the region (phaseA out)
  //  [201.3M, 213.9M)  w1hi|w1lo|w2hi|w2lo (bf16, transposed)
  //  fbuf/cbuf (8 MB each) live in d_out scratch (dead until GEMM2).
  const size_t NEEDED = 213909504;
  if (ws_size < NEEDED) return;  // clean diagnostic fail instead of OOB fault

  char* w8 = (char*)d_ws;
  float* xb = (float*)(w8);
  unsigned short* zbf = (unsigned short*)(w8 + 67108864);
  unsigned short* yhi = (unsigned short*)(w8 + 100663296);
  unsigned short* xhi = (unsigned short*)(w8 + 134217728);
  float* hs = (float*)(w8 + 134217728);            // overlays xhi region
  unsigned short* w1hi = (unsigned short*)(w8 + 201326592);
  unsigned short* w1lo = (unsigned short*)(w8 + 205520896);
  unsigned short* w2hi = (unsigned short*)(w8 + 209715200);
  unsigned short* w2lo = (unsigned short*)(w8 + 211812352);
  float* fbuf = (float*)d_out;                     // scratch until GEMM2
  float* cbuf = fbuf + (size_t)BATCH * NCHUNK * DIM;

  // 1. fused RMSNorm + bf16 round of x (hi only; wave per row)
  splitx_kernel<<<MROWS / 4, 256, 0, stream>>>(x, norm_w, xhi);

  // 2. both weight transpose+splits in one launch
  splitw2_kernel<<<dim3(64, 32, 2), 256, 0, stream>>>(
      in_w, w1hi, w1lo, out_w, w2hi, w2lo);

  // 3. GEMM1a (exact-B bf16x2 on proven 4-tile staging; Alo slot fed xhi,
  //    staged but never consumed): xb = xhi @ (w1hi+w1lo)[:1024]  fp32
  gemm1a_kernel<<<dim3(8, 128), 256, 0, stream>>>(xhi, xhi, w1hi, w1lo, xb);

  // 4. GEMM1z (bf16x1, BK=64): z = xhi @ w1hi[1024:]   bf16 out
  gemm1z_kernel<<<dim3(8, 128), 256, 0, stream>>>(
      xhi, w1hi + (size_t)1024 * 1024, zbf);

  // 5. conv + silu + local scan (CHUNK=8, float4/thread)
  phaseA_kernel<<<dim3(NCHUNK, BATCH), 256, 0, stream>>>(
      xb, conv_w, conv_b, decay, hs, fbuf);

  // 6. chunk carry propagation (16-deep prefetch)
  phaseB_kernel<<<dim3(DIM / 256, BATCH), 256, 0, stream>>>(decay, fbuf, cbuf);

  // 7. carry injection + gated rmsnorm * silu(z) -> yhi (bf16)
  phaseC_kernel<<<MROWS / 4, 256, 0, stream>>>(zbf, hs, cbuf, decay, gate_w, yhi);

  // 8. GEMM2 (bf16x1, BK=64): out = x * res_scale + y @ out_w
  gemm2_kernel<<<dim3(8, 128), 256, 0, stream>>>(yhi, w2hi, out, x, res_scale);
}

// Round 11
// 392.522 us; speedup vs baseline: 1.0954x; 1.0313x over previous
//
#include <hip/hip_runtime.h>
#include <cstddef>

// Problem constants (match reference)
#define BATCH 4
#define SEQ   4096
#define DIM   1024
#define KCONV 4
#define EPSV  1e-6f
#define MROWS (BATCH * SEQ)      // 16384
#define CHUNK 8
#define NCHUNK (SEQ / CHUNK)     // 512

using short8v = __attribute__((ext_vector_type(8))) short;  // 8 bf16 (4 VGPRs)
using f32x4   = __attribute__((ext_vector_type(4))) float;  // MFMA acc

// bf16 helpers (RNE)
__device__ __forceinline__ unsigned short f2bf_rne(float f) {
  unsigned int u = __float_as_uint(f);
  u += 0x7FFFu + ((u >> 16) & 1u);
  return (unsigned short)(u >> 16);
}
__device__ __forceinline__ float bf2f(unsigned short h) {
  return __uint_as_float((unsigned int)h << 16);
}

// Full-wave (64-lane) sum reduction; all lanes get the total.
__device__ __forceinline__ float wave_reduce_sum(float v) {
#pragma unroll
  for (int off = 32; off > 0; off >>= 1)
    v += __shfl_xor(v, off, 64);
  return v;
}

// ---------------------------------------------------------------------------
// splitx: fused input RMSNorm + bf16 round (hi only). One WAVE per row.
// ---------------------------------------------------------------------------
__global__ __launch_bounds__(256) void splitx_kernel(
    const float* __restrict__ x, const float* __restrict__ norm_w,
    unsigned short* __restrict__ Xhi) {
  const int row = blockIdx.x * 4 + (threadIdx.x >> 6);
  const int lane = threadIdx.x & 63;
  float4 v[4];
  float ss = 0.f;
#pragma unroll
  for (int i = 0; i < 4; ++i) {
    v[i] = *reinterpret_cast<const float4*>(
        &x[(size_t)row * DIM + lane * 4 + i * 256]);
    ss += v[i].x * v[i].x + v[i].y * v[i].y + v[i].z * v[i].z + v[i].w * v[i].w;
  }
  const float rstd = rsqrtf(wave_reduce_sum(ss) * (1.0f / DIM) + EPSV);
#pragma unroll
  for (int i = 0; i < 4; ++i) {
    const int d4 = lane * 4 + i * 256;
    const float4 w = *reinterpret_cast<const float4*>(&norm_w[d4]);
    ushort4 hh;
    hh.x = f2bf_rne(v[i].x * rstd * w.x);
    hh.y = f2bf_rne(v[i].y * rstd * w.y);
    hh.z = f2bf_rne(v[i].z * rstd * w.z);
    hh.w = f2bf_rne(v[i].w * rstd * w.w);
    *reinterpret_cast<ushort4*>(&Xhi[(size_t)row * DIM + d4]) = hh;
  }
}

// ---------------------------------------------------------------------------
// splitw2: both weights in one launch (blockIdx.z selects).
// W[K][N] fp32 -> transposed bf16 hi/lo Wt[N][K] via 32x32 LDS tiles.
// ---------------------------------------------------------------------------
__global__ __launch_bounds__(256) void splitw2_kernel(
    const float* __restrict__ W0, unsigned short* __restrict__ W0hi,
    unsigned short* __restrict__ W0lo, const float* __restrict__ W1,
    unsigned short* __restrict__ W1hi, unsigned short* __restrict__ W1lo) {
  const float* W; unsigned short *Whi, *Wlo; int N;
  if (blockIdx.z == 0) { W = W0; Whi = W0hi; Wlo = W0lo; N = 2048; }
  else {
    if (blockIdx.x >= 32) return;   // uniform: whole block exits together
    W = W1; Whi = W1hi; Wlo = W1lo; N = 1024;
  }
  const int K = 1024;
  __shared__ float t[32][33];
  const int n0 = blockIdx.x * 32, k0 = blockIdx.y * 32;
  const int c = threadIdx.x & 31, r = threadIdx.x >> 5;  // r: 0..7
#pragma unroll
  for (int i = 0; i < 4; ++i)
    t[r + i * 8][c] = W[(size_t)(k0 + r + i * 8) * N + n0 + c];
  __syncthreads();
#pragma unroll
  for (int i = 0; i < 4; ++i) {
    const int n = n0 + r + i * 8, k = k0 + c;
    const float v = t[c][r + i * 8];
    const unsigned short h = f2bf_rne(v);
    Whi[(size_t)n * K + k] = h;
    Wlo[(size_t)n * K + k] = f2bf_rne(v - bf2f(h));
  }
}

// ---------------------------------------------------------------------------
// Shared GEMM body.  C[M][N] = A[M][1024] * B^T[N][1024].
//   NT=4: exact-B bf16x2 on the PROVEN 4-tile layout (BK=32, 32KB LDS), but
//         the dead Alo tile's two staging loads are SKIPPED (its LDS region
//         holds garbage and is never read — round 10 passed with it staged;
//         skipping the stores cannot change any read value). 6 loads/step.
//   NT=2: plain bf16, BK=64, 2 tiles [128][64] (32KB), XOR sub-step advance.
// global_load_lds width-16, linear dest; XOR swizzle b ^= ((b>>7)&7)<<4 on
// SOURCE logical byte and frag READ byte (involution, both sides).
// RULE: offsets vs swizzled addrs must COMPOSE with the XOR — +64B within a
// row is addr^64; tile offsets (bit 13+) commute (round-6 lesson).
// ---------------------------------------------------------------------------
template <int NT, bool RESID, bool OBF16>
__device__ __forceinline__ void gemm_body(
    const unsigned short* __restrict__ Ahi, const unsigned short* __restrict__ Alo,
    const unsigned short* __restrict__ Bhi, const unsigned short* __restrict__ Blo,
    float* __restrict__ Cf, unsigned short* __restrict__ Ch, int N, int lda,
    const float* __restrict__ resid, const float* __restrict__ res_scale) {
  constexpr int BK = (NT == 4) ? 32 : 64;
  __shared__ __align__(16) unsigned short lds[16384];  // 32 KB

  const int tid = threadIdx.x;
  const int lane = tid & 63;
  const int wr = tid >> 7;         // wave quadrant row (0..1)
  const int wc = (tid >> 6) & 1;   // wave quadrant col (0..1)

  // XCD-aware block swizzle (nwg divisible by 8 for all GEMMs here)
  const int nwg = gridDim.x * gridDim.y;
  int id = blockIdx.y * gridDim.x + blockIdx.x;
  id = (id & 7) * (nwg >> 3) + (id >> 3);
  const int bx = id % gridDim.x;
  const int by = id / gridDim.x;
  const int bm = by * 128;
  const int bn = bx * 128;

  // Staging: 16B per thread per slot. Linear LDS byte o; tensor t;
  // within-tile ot; source logical byte b = ot^swz(ot).
  const unsigned short* pg[8];
  unsigned int lofs[8];
#pragma unroll
  for (int i = 0; i < 8; ++i) {
    const int o = tid * 16 + i * 4096;
    int t, r, ck;
    if constexpr (NT == 4) {
      t = o >> 13;
      const int ot = o & 8191;
      const int b = ot ^ (((ot >> 7) & 7) << 4);
      r = b >> 6; ck = (b & 63) >> 1;
    } else {
      t = o >> 14;
      const int ot = o & 16383;
      const int b = ot ^ (((ot >> 7) & 7) << 4);
      r = b >> 7; ck = (b & 127) >> 1;
    }
    const unsigned short* base;
    bool aside;
    if constexpr (NT == 4) {
      base = (t == 0) ? Ahi : (t == 1) ? Alo : (t == 2) ? Bhi : Blo;
      aside = (t < 2);
    } else {
      base = (t == 0) ? Ahi : Bhi;
      aside = (t == 0);
    }
    const int stride = aside ? lda : 1024;
    const int rowg = (aside ? bm : bn) + r;
    pg[i] = base + (size_t)rowg * stride + ck;
    lofs[i] = (unsigned int)(o >> 1);
  }

  // Fragment read offsets (ushort idx), swizzled. B tiles at +8192 ushorts.
  constexpr int ROWB = (NT == 4) ? 64 : 128;
  unsigned int aoff[4], boff[4];
#pragma unroll
  for (int i = 0; i < 4; ++i) {
    int ba = (wr * 64 + i * 16 + (lane & 15)) * ROWB + (lane >> 4) * 16;
    ba ^= ((ba >> 7) & 7) << 4;
    aoff[i] = (unsigned int)(ba >> 1);
    int bb = (wc * 64 + i * 16 + (lane & 15)) * ROWB + (lane >> 4) * 16;
    bb ^= ((bb >> 7) & 7) << 4;
    boff[i] = (unsigned int)(bb >> 1) + 8192;
  }

  f32x4 acc[4][4];
#pragma unroll
  for (int mi = 0; mi < 4; ++mi)
#pragma unroll
    for (int ni = 0; ni < 4; ++ni) {
      acc[mi][ni][0] = 0.f; acc[mi][ni][1] = 0.f;
      acc[mi][ni][2] = 0.f; acc[mi][ni][3] = 0.f;
    }

  for (int k0 = 0; k0 < 1024; k0 += BK) {
#pragma unroll
    for (int i = 0; i < 8; ++i) {
      if constexpr (NT == 4)
        if (i == 2 || i == 3) continue;   // dead Alo tile: never read
      __builtin_amdgcn_global_load_lds(
          (const __attribute__((address_space(1))) void*)(pg[i] + k0),
          (__attribute__((address_space(3))) void*)(&lds[lofs[i]]), 16, 0, 0);
    }
    __syncthreads();  // compiler drains vmcnt before s_barrier

    if constexpr (NT == 4) {
      // exact-B: C += Ahi*(Bhi + Blo).
      short8v bh[4], bl[4];
#pragma unroll
      for (int ni = 0; ni < 4; ++ni) {
        bh[ni] = *reinterpret_cast<const short8v*>(&lds[boff[ni]]);
        bl[ni] = *reinterpret_cast<const short8v*>(&lds[boff[ni] + 4096]);
      }
#pragma unroll
      for (int mi = 0; mi < 4; ++mi) {
        const short8v ah = *reinterpret_cast<const short8v*>(&lds[aoff[mi]]);
#pragma unroll
        for (int ni = 0; ni < 4; ++ni) {
          acc[mi][ni] = __builtin_amdgcn_mfma_f32_16x16x32_bf16(ah, bh[ni], acc[mi][ni], 0, 0, 0);
          acc[mi][ni] = __builtin_amdgcn_mfma_f32_16x16x32_bf16(ah, bl[ni], acc[mi][ni], 0, 0, 0);
        }
      }
    } else {
#pragma unroll
      for (int kk = 0; kk < 2; ++kk) {   // two 32-k sub-steps within BK=64
        short8v bh[4];
#pragma unroll
        for (int ni = 0; ni < 4; ++ni)
          bh[ni] = *reinterpret_cast<const short8v*>(&lds[boff[ni] ^ (kk * 32)]);
#pragma unroll
        for (int mi = 0; mi < 4; ++mi) {
          const short8v ah =
              *reinterpret_cast<const short8v*>(&lds[aoff[mi] ^ (kk * 32)]);
#pragma unroll
          for (int ni = 0; ni < 4; ++ni)
            acc[mi][ni] = __builtin_amdgcn_mfma_f32_16x16x32_bf16(ah, bh[ni], acc[mi][ni], 0, 0, 0);
        }
      }
    }
    __syncthreads();
  }

  // Epilogue: C/D layout col=lane&15, row=(lane>>4)*4+reg (verified).
  const float rscale = RESID ? res_scale[0] : 0.0f;
#pragma unroll
  for (int mi = 0; mi < 4; ++mi) {
    const int row0 = bm + wr * 64 + mi * 16 + (lane >> 4) * 4;
#pragma unroll
    for (int ni = 0; ni < 4; ++ni) {
      const int col = bn + wc * 64 + ni * 16 + (lane & 15);
#pragma unroll
      for (int r = 0; r < 4; ++r) {
        const size_t idx = (size_t)(row0 + r) * N + col;
        float v = acc[mi][ni][r];
        if constexpr (RESID) v = fmaf(resid[idx], rscale, v);
        if constexpr (OBF16) Ch[idx] = f2bf_rne(v);
        else                 Cf[idx] = v;
      }
    }
  }
}

// Distinctly named wrappers so rocprof rows are attributable per GEMM.
__global__ __launch_bounds__(256) void gemm1a_kernel(
    const unsigned short* Ahi, const unsigned short* Alo,
    const unsigned short* Bhi, const unsigned short* Blo, float* Cf) {
  gemm_body<4, false, false>(Ahi, Alo, Bhi, Blo, Cf, nullptr, DIM, 1024,
                             nullptr, nullptr);
}
__global__ __launch_bounds__(256) void gemm1z_kernel(
    const unsigned short* Ahi, const unsigned short* Bhi, unsigned short* Ch) {
  gemm_body<2, false, true>(Ahi, nullptr, Bhi, nullptr, nullptr, Ch, DIM,
                            1024, nullptr, nullptr);
}
__global__ __launch_bounds__(256) void gemm2_kernel(
    const unsigned short* Ahi, const unsigned short* Bhi, float* Cf,
    const float* resid, const float* res_scale) {
  gemm_body<2, true, false>(Ahi, nullptr, Bhi, nullptr, Cf, nullptr, DIM,
                            1024, resid, res_scale);
}

// ---------------------------------------------------------------------------
// Phase A: depthwise causal conv(K=4) + bias + silu + LOCAL scan, CHUNK=8.
// Grid (NCHUNK, BATCH); 256 threads x float4 -> 1024 d's. 16B/lane loads.
// ---------------------------------------------------------------------------
__global__ __launch_bounds__(256) void phaseA_kernel(
    const float* __restrict__ xb, const float* __restrict__ conv_w,
    const float* __restrict__ conv_b, const float* __restrict__ decay,
    float* __restrict__ hs, float* __restrict__ fbuf) {
  const int d = threadIdx.x * 4;
  const int c = blockIdx.x;
  const int b = blockIdx.y;
  const int t0 = c * CHUNK;

  float cw[4][4];
#pragma unroll
  for (int j = 0; j < 4; ++j) {
    const float4 w = *reinterpret_cast<const float4*>(&conv_w[(d + j) * 4]);
    cw[j][0] = w.x; cw[j][1] = w.y; cw[j][2] = w.z; cw[j][3] = w.w;
  }
  const float4 cb4 = *reinterpret_cast<const float4*>(&conv_b[d]);
  const float4 dc4 = *reinterpret_cast<const float4*>(&decay[d]);
  const float cb[4] = {cb4.x, cb4.y, cb4.z, cb4.w};
  const float a[4] = {
      1.0f / (1.0f + expf(-dc4.x)), 1.0f / (1.0f + expf(-dc4.y)),
      1.0f / (1.0f + expf(-dc4.z)), 1.0f / (1.0f + expf(-dc4.w))};

  const size_t base = ((size_t)b * SEQ + t0) * DIM + d;
  float p1[4] = {0, 0, 0, 0}, p2[4] = {0, 0, 0, 0}, p3[4] = {0, 0, 0, 0};
  if (t0 >= 1) {
    const float4 v = *reinterpret_cast<const float4*>(&xb[base - DIM]);
    p1[0] = v.x; p1[1] = v.y; p1[2] = v.z; p1[3] = v.w;
  }
  if (t0 >= 2) {
    const float4 v = *reinterpret_cast<const float4*>(&xb[base - 2 * DIM]);
    p2[0] = v.x; p2[1] = v.y; p2[2] = v.z; p2[3] = v.w;
  }
  if (t0 >= 3) {
    const float4 v = *reinterpret_cast<const float4*>(&xb[base - 3 * DIM]);
    p3[0] = v.x; p3[1] = v.y; p3[2] = v.z; p3[3] = v.w;
  }

  float h[4] = {0, 0, 0, 0};
  size_t src = base;
#pragma unroll
  for (int t = 0; t < CHUNK; ++t) {
    const float4 cv = *reinterpret_cast<const float4*>(&xb[src]);
    const float cur[4] = {cv.x, cv.y, cv.z, cv.w};
    float4 ho;
    float* hp = &ho.x;
#pragma unroll
    for (int j = 0; j < 4; ++j) {
      const float conv = fmaf(cw[j][0], p3[j],
                         fmaf(cw[j][1], p2[j],
                         fmaf(cw[j][2], p1[j],
                         fmaf(cw[j][3], cur[j], cb[j]))));
      const float u = conv / (1.0f + expf(-conv));  // silu
      h[j] = fmaf(a[j], h[j], u);
      hp[j] = h[j];
      p3[j] = p2[j]; p2[j] = p1[j]; p1[j] = cur[j];
    }
    *reinterpret_cast<float4*>(&hs[src]) = ho;
    src += DIM;
  }
  float4 fo; fo.x = h[0]; fo.y = h[1]; fo.z = h[2]; fo.w = h[3];
  *reinterpret_cast<float4*>(&fbuf[((size_t)b * NCHUNK + c) * DIM + d]) = fo;
}

// ---------------------------------------------------------------------------
// Phase B: sequential carry propagation across 512 chunks, 16-deep prefetch.
// Also emits l2a[d] = log2(sigmoid(decay[d])) once (hoists phaseC's
// per-element transcendentals; same ops, bit-identical downstream).
// Grid: (DIM/256, BATCH).
// ---------------------------------------------------------------------------
__global__ __launch_bounds__(256) void phaseB_kernel(
    const float* __restrict__ decay, const float* __restrict__ fbuf,
    float* __restrict__ cbuf, float* __restrict__ l2a) {
  const int d = blockIdx.x * 256 + threadIdx.x;
  const int b = blockIdx.y;
  const float a = 1.0f / (1.0f + expf(-decay[d]));
  const float la = __log2f(a);
  if (b == 0) l2a[d] = la;
  const float aL = exp2f((float)CHUNK * la);
  const float* fp = fbuf + (size_t)b * NCHUNK * DIM + d;
  float* cp = cbuf + (size_t)b * NCHUNK * DIM + d;
  float carry = 0.f;
  for (int c0 = 0; c0 < NCHUNK; c0 += 16) {
    float v[16];
#pragma unroll
    for (int i = 0; i < 16; ++i) v[i] = fp[(size_t)(c0 + i) * DIM];
#pragma unroll
    for (int i = 0; i < 16; ++i) {
      cp[(size_t)(c0 + i) * DIM] = carry;
      carry = fmaf(aL, carry, v[i]);
    }
  }
}

// ---------------------------------------------------------------------------
// Phase C: h_full = hs_local + a^(j+1)*carry; y = rmsnorm(h_full, gate_w) *
// silu(z) -> bf16. One WAVE per row; 4 rows per block. CHUNK=8.
// Uses precomputed l2a[d] (one exp2f per element instead of exp+log+exp2).
// ---------------------------------------------------------------------------
__global__ __launch_bounds__(256) void phaseC_kernel(
    const unsigned short* __restrict__ z, const float* __restrict__ hs,
    const float* __restrict__ cbuf, const float* __restrict__ l2a,
    const float* __restrict__ gate_w, unsigned short* __restrict__ Yhi) {
  const int row = blockIdx.x * 4 + (threadIdx.x >> 6);
  const int lane = threadIdx.x & 63;
  const int b = row >> 12;             // SEQ = 4096
  const int t = row & (SEQ - 1);
  const int c = t >> 3;                // CHUNK = 8
  const float e = (float)((t & (CHUNK - 1)) + 1);

  float hv[16];
  float ss = 0.f;
#pragma unroll
  for (int i = 0; i < 4; ++i) {
    const int d4 = lane * 4 + i * 256;
    const float4 la4 = *reinterpret_cast<const float4*>(&l2a[d4]);
    const float4 cv = *reinterpret_cast<const float4*>(
        &cbuf[((size_t)b * NCHUNK + c) * DIM + d4]);
    const float4 hl = *reinterpret_cast<const float4*>(
        &hs[(size_t)row * DIM + d4]);
    const float la[4] = {la4.x, la4.y, la4.z, la4.w};
    const float cr[4] = {cv.x, cv.y, cv.z, cv.w};
    const float hh[4] = {hl.x, hl.y, hl.z, hl.w};
#pragma unroll
    for (int j = 0; j < 4; ++j) {
      const float ae = exp2f(e * la[j]);
      const float v = fmaf(ae, cr[j], hh[j]);
      hv[i * 4 + j] = v;
      ss = fmaf(v, v, ss);
    }
  }
  const float rstd = rsqrtf(wave_reduce_sum(ss) * (1.0f / DIM) + EPSV);
#pragma unroll
  for (int i = 0; i < 4; ++i) {
    const int d4 = lane * 4 + i * 256;
    const ushort4 zs = *reinterpret_cast<const ushort4*>(
        &z[(size_t)row * DIM + d4]);
    const float4 gw = *reinterpret_cast<const float4*>(&gate_w[d4]);
    const float zf[4] = {bf2f(zs.x), bf2f(zs.y), bf2f(zs.z), bf2f(zs.w)};
    const float gf[4] = {gw.x, gw.y, gw.z, gw.w};
    ushort4 yo;
    unsigned short* yp = &yo.x;
#pragma unroll
    for (int j = 0; j < 4; ++j) {
      const float sz = zf[j] / (1.0f + expf(-zf[j]));  // silu(z)
      yp[j] = f2bf_rne(hv[i * 4 + j] * rstd * gf[j] * sz);
    }
    *reinterpret_cast<ushort4*>(&Yhi[(size_t)row * DIM + d4]) = yo;
  }
}

// ---------------------------------------------------------------------------
extern "C" void kernel_launch(void* const* d_in, const int* in_sizes, int n_in,
                              void* d_out, int out_size, void* d_ws,
                              size_t ws_size, hipStream_t stream) {
  const float* x = (const float*)d_in[0];
  const float* norm_w = (const float*)d_in[1];
  const float* in_w = (const float*)d_in[2];
  const float* conv_w = (const float*)d_in[3];
  const float* conv_b = (const float*)d_in[4];
  const float* decay = (const float*)d_in[5];
  const float* gate_w = (const float*)d_in[6];
  const float* out_w = (const float*)d_in[7];
  const float* res_scale = (const float*)d_in[8];
  float* out = (float*)d_out;

  // Workspace layout (bytes), peak 213,909,504 (~204 MiB):
  //  [0,       67.1M)  xb fp32 [M][1024]   (GEMM1a out; phaseA in)
  //  [67.1M,  100.7M)  z  bf16 [M][1024]   (GEMM1z out; phaseC in)
  //  [100.7M, 134.2M)  yhi bf16 [M][1024]  (phaseC out; GEMM2 A)
  //  [134.2M, 201.3M)  xhi bf16 (GEMM1 A) — dead after GEMM1z ->
  //                    hs fp32 [M][1024] overlays the region (phaseA out)
  //  [201.3M, 213.9M)  w1hi|w1lo|w2hi|w2lo (bf16, transposed)
  //  fbuf/cbuf (8 MB each) + l2a (4 KB) live in d_out scratch.
  const size_t NEEDED = 213909504;
  if (ws_size < NEEDED) return;  // clean diagnostic fail instead of OOB fault

  char* w8 = (char*)d_ws;
  float* xb = (float*)(w8);
  unsigned short* zbf = (unsigned short*)(w8 + 67108864);
  unsigned short* yhi = (unsigned short*)(w8 + 100663296);
  unsigned short* xhi = (unsigned short*)(w8 + 134217728);
  float* hs = (float*)(w8 + 134217728);            // overlays xhi region
  unsigned short* w1hi = (unsigned short*)(w8 + 201326592);
  unsigned short* w1lo = (unsigned short*)(w8 + 205520896);
  unsigned short* w2hi = (unsigned short*)(w8 + 209715200);
  unsigned short* w2lo = (unsigned short*)(w8 + 211812352);
  float* fbuf = (float*)d_out;                     // scratch until GEMM2
  float* cbuf = fbuf + (size_t)BATCH * NCHUNK * DIM;
  float* l2a  = cbuf + (size_t)BATCH * NCHUNK * DIM;

  // 1. fused RMSNorm + bf16 round of x (hi only; wave per row)
  splitx_kernel<<<MROWS / 4, 256, 0, stream>>>(x, norm_w, xhi);

  // 2. both weight transpose+splits in one launch
  splitw2_kernel<<<dim3(64, 32, 2), 256, 0, stream>>>(
      in_w, w1hi, w1lo, out_w, w2hi, w2lo);

  // 3. GEMM1a (exact-B bf16x2, dead-tile loads skipped):
  //    xb = xhi @ (w1hi+w1lo)[:1024]  fp32
  gemm1a_kernel<<<dim3(8, 128), 256, 0, stream>>>(xhi, xhi, w1hi, w1lo, xb);

  // 4. GEMM1z (bf16x1, BK=64): z = xhi @ w1hi[1024:]   bf16 out
  gemm1z_kernel<<<dim3(8, 128), 256, 0, stream>>>(
      xhi, w1hi + (size_t)1024 * 1024, zbf);

  // 5. conv + silu + local scan (CHUNK=8, float4/thread)
  phaseA_kernel<<<dim3(NCHUNK, BATCH), 256, 0, stream>>>(
      xb, conv_w, conv_b, decay, hs, fbuf);

  // 6. chunk carry propagation (16-deep prefetch) + l2a emit
  phaseB_kernel<<<dim3(DIM / 256, BATCH), 256, 0, stream>>>(
      decay, fbuf, cbuf, l2a);

  // 7. carry injection + gated rmsnorm * silu(z) -> yhi (bf16)
  phaseC_kernel<<<MROWS / 4, 256, 0, stream>>>(zbf, hs, cbuf, l2a, gate_w, yhi);

  // 8. GEMM2 (bf16x1, BK=64): out = x * res_scale + y @ out_w
  gemm2_kernel<<<dim3(8, 128), 256, 0, stream>>>(yhi, w2hi, out, x, res_scale);
}